// Round 9
// baseline (168.484 us; speedup 1.0000x reference)
//
#include <hip/hip_runtime.h>
#include <hip/hip_fp16.h>
#include <math.h>

// ConvCapsuleLayer v8: fused conv+routing, tuned for 4 blocks/CU (LDS = 40960 B exactly).
//   conv:    MFMA fp16, depth-1 A-prefetch + depth-2 B-prefetch (unchanged from v7).
//   routing: thread = (p, co, ao-half); votes in vl[p][cp][ao][co pad17] (34816 B),
//            bias in registers, logit unpadded, direct coalesced reg->global output.
// x: [16,32,32,8,32] f32; W: [5,5,32,256] f32; b: [1,1,16,16] f32
// out: [16,32,32,16,16] f32

typedef _Float16 f16;
typedef __attribute__((ext_vector_type(2))) _Float16 f16x2;
typedef __attribute__((ext_vector_type(8))) _Float16 f16x8;
typedef __attribute__((ext_vector_type(4))) float f32x4;

#define STRIDE_CI 1944   // hw per ci slice: 5*12*32=1920 (+24)
#define XB_OFF 0
#define WT_OFF 9437184   // bytes: 16*32*36*256*2

// vote LDS index: [p][cp][ao][co] with co-dim padded to 17 dwords
#define VIDX(p, cp, ao, co) ((((p)*4 + (cp))*16 + (ao))*17 + (co))

static __device__ __forceinline__ float2 up16(unsigned int u) {
    union { unsigned int u; f16 h[2]; } c; c.u = u;
    return make_float2((float)c.h[0], (float)c.h[1]);
}

static __device__ __forceinline__ float fdot2u(unsigned int a, unsigned int b, float c) {
#if __has_builtin(__builtin_amdgcn_fdot2)
    union { unsigned int u; f16x2 h; } ua, ub;
    ua.u = a; ub.u = b;
    return __builtin_amdgcn_fdot2(ua.h, ub.h, c, false);
#else
    const float2 fa = up16(a), fb = up16(b);
    return c + fa.x * fb.x + fa.y * fb.y;
#endif
}

__global__ void prep(const float* __restrict__ x, const float* __restrict__ W,
                     f16* __restrict__ xb, f16* __restrict__ Wt) {
    __shared__ f16 lw[32 * 260];
    const int tid = threadIdx.x;
    const int bid = blockIdx.x;
    if (bid < 4608) {
        const int e4 = (bid * 256 + tid) * 4;
        const int c = e4 & 255;
        const int pix = e4 >> 8;
        const int wp = pix % 36;
        const int t = pix / 36;
        const int h = t & 31;
        const int b = t >> 5;
        const int w = wp - 2;
        f16 o[4] = {(f16)0.f, (f16)0.f, (f16)0.f, (f16)0.f};
        if ((unsigned)w < 32u) {
            const float4 v = *(const float4*)&x[(((b * 32 + h) * 32 + w) * 256) + c];
            o[0] = (f16)v.x; o[1] = (f16)v.y; o[2] = (f16)v.z; o[3] = (f16)v.w;
        }
        *(unsigned long long*)&xb[e4] = *(unsigned long long*)o;
    } else {
        const int k5 = bid - 4608;
        for (int rep = 0; rep < 32; ++rep) {
            const int idx = rep * 256 + tid;
            const int ai = idx >> 8, cc = idx & 255;
            lw[ai * 260 + cc] = (f16)W[(k5 * 32 + ai) * 256 + cc];
        }
        __syncthreads();
        for (int rep = 0; rep < 32; ++rep) {
            const int o = rep * 256 + tid;
            const int cc = o >> 5, ai = o & 31;
            Wt[k5 * 8192 + o] = lw[ai * 260 + cc];
        }
    }
}

// ---------------- fused conv + routing ----------------
__global__ __launch_bounds__(256, 4)
void caps_v8(const f16* __restrict__ xb, const f16* __restrict__ Wt,
             const float* __restrict__ bptr, float* __restrict__ out) {
    // conv phase: patch fp16[8*1944] = 31104 B
    // route phase: vl u32 [p8][cp4][ao16][co pad17] = 34816 B (aliases patch)
    __shared__ __align__(16) unsigned char smraw[34816];
    f16* patch = (f16*)smraw;
    unsigned int* vl = (unsigned int*)smraw;
    __shared__ __align__(16) uint4 route_l[8 * 16];   // fp16 ci-pair quads per (p,co)
    __shared__ float logit_l[8 * 8 * 16];             // [p][ci][co] (co-contiguous access)
    // total LDS: 34816 + 2048 + 4096 = 40960 B exactly -> 4 blocks/CU

    const int tid = threadIdx.x;
    const int lane = tid & 63;
    const int wv = tid >> 6;
    const int bid = blockIdx.x;
    const int w0 = (bid & 3) * 8;
    const int h = (bid >> 2) & 31;
    const int b = bid >> 7;

    // routing thread mapping (fixed per thread)
    const int rp  = tid >> 5;
    const int rco = (tid >> 1) & 15;
    const int aoh = tid & 1;
    // bias: 8 consecutive floats per thread, in registers
    const float4 bia0 = *(const float4*)&bptr[rco * 16 + aoh * 8];
    const float4 bia1 = *(const float4*)&bptr[rco * 16 + aoh * 8 + 4];

    // ---- stage input patch ----
    for (int e = tid; e < 1920; e += 256) {
        const int pos = e >> 5;
        const int ci = (e >> 2) & 7;
        const int s = e & 3;
        const int dh = pos / 12, dw = pos - dh * 12;
        const int gh = h + dh - 2;
        f16x8 v = {};
        if ((unsigned)gh < 32u)
            v = *(const f16x8*)&xb[(((b * 32 + gh) * 36) + (w0 + dw)) * 256 + ci * 32 + s * 8];
        *(f16x8*)&patch[ci * STRIDE_CI + pos * 32 + s * 8] = v;
    }
    __syncthreads();

    // ---- conv: M=64 (p*8+ci), N=256 (co*16+ao), K=800 ----
    const int g = lane >> 4;
    const int q = lane & 15;
    const f16* aptr = patch + (lane & 7) * STRIDE_CI + ((lane >> 3) & 1) * 32 + g * 8;
    const f16* bbase = Wt + (wv * 64 + q) * 32 + g * 8;

    f32x4 acc[4][4];
#pragma unroll
    for (int rb = 0; rb < 4; ++rb)
#pragma unroll
        for (int ct = 0; ct < 4; ++ct) acc[rb][ct] = (f32x4)0.f;

    f16x8 Bc[4], Bn[4];
    f16x8 Ac[4], An[4];
#pragma unroll
    for (int ct = 0; ct < 4; ++ct) {
        Bc[ct] = *(const f16x8*)(bbase + ct * 512);            // k5 = 0
        Bn[ct] = *(const f16x8*)(bbase + 8192 + ct * 512);     // k5 = 1
    }
#pragma unroll
    for (int rb = 0; rb < 4; ++rb)
        Ac[rb] = *(const f16x8*)(aptr + rb * 64);              // k5 = 0

    int k5 = 0;
#pragma unroll
    for (int kh = 0; kh < 5; ++kh) {
#pragma unroll
        for (int kw = 0; kw < 5; ++kw) {
            if (k5 < 24) {                                     // prefetch A for k5+1
                const int n = k5 + 1;
                const f16* apn = aptr + ((n / 5) * 12 + (n % 5)) * 32;
#pragma unroll
                for (int rb = 0; rb < 4; ++rb)
                    An[rb] = *(const f16x8*)(apn + rb * 64);
            }
            f16x8 Bf[4];
            if (k5 < 23) {                                     // prefetch B for k5+2
                const f16* bf = bbase + (k5 + 2) * 8192;
#pragma unroll
                for (int ct = 0; ct < 4; ++ct)
                    Bf[ct] = *(const f16x8*)(bf + ct * 512);
            }
#pragma unroll
            for (int rb = 0; rb < 4; ++rb)
#pragma unroll
                for (int ct = 0; ct < 4; ++ct)
                    acc[rb][ct] = __builtin_amdgcn_mfma_f32_16x16x32_f16(
                        Ac[rb], Bc[ct], acc[rb][ct], 0, 0, 0);
#pragma unroll
            for (int rb = 0; rb < 4; ++rb) Ac[rb] = An[rb];
#pragma unroll
            for (int ct = 0; ct < 4; ++ct) { Bc[ct] = Bn[ct]; Bn[ct] = Bf[ct]; }
            ++k5;
        }
    }
    // acc[rb][ct][j] = votes[p=rb*2+(g>>1)][ci=(g&1)*4+j][co=wv*4+ct][ao=q]
    __syncthreads();   // patch dead — safe to overwrite with vl

    // ---- votes -> LDS (fp16 pairs, ci-adjacent; cp = ci>>1) ----
#pragma unroll
    for (int rb = 0; rb < 4; ++rb) {
        const int p = rb * 2 + (g >> 1);
        const int cpb = (g & 1) * 2;
#pragma unroll
        for (int ct = 0; ct < 4; ++ct) {
            const int co = wv * 4 + ct;
            union { f16 h[2]; unsigned int u; } c0, c1;
            c0.h[0] = (f16)acc[rb][ct].x; c0.h[1] = (f16)acc[rb][ct].y;
            c1.h[0] = (f16)acc[rb][ct].z; c1.h[1] = (f16)acc[rb][ct].w;
            vl[VIDX(p, cpb, q, co)] = c0.u;
            vl[VIDX(p, cpb + 1, q, co)] = c1.u;
        }
    }
    __syncthreads();

    // ---- routing core: thread = (rp, rco, aoh); owns ao = aoh*8 .. +7 ----
    unsigned int* route_d = (unsigned int*)route_l;

    for (int it = 0; it < 3; ++it) {
        if (it > 0) {
            // softmax over co; pack route as fp16 ci-pairs into route_l[p*16+co]
            for (int i = tid; i < 1024; i += 256) {
                const int pp = i >> 7, ci = (i >> 4) & 7, co = i & 15;
                float lg = logit_l[(pp * 8 + ci) * 16 + co];
                float mx = lg;
#pragma unroll
                for (int m = 1; m < 16; m <<= 1) mx = fmaxf(mx, __shfl_xor(mx, m));
                float e = __expf(lg - mx);
                float s = e;
#pragma unroll
                for (int m = 1; m < 16; m <<= 1) s += __shfl_xor(s, m);
                const float r = e * __builtin_amdgcn_rcpf(s);
                const float rother = __shfl_xor(r, 16);   // partner ci^1
                if (((tid >> 4) & 1) == 0) {              // even-ci lanes pack
                    union { f16 h[2]; unsigned int u; } pk;
                    pk.h[0] = (f16)r; pk.h[1] = (f16)rother;
                    route_d[(pp * 16 + co) * 4 + (ci >> 1)] = pk.u;
                }
            }
            __syncthreads();
        }

        // preact + squash: 8 ao values in-lane
        uint4 r4;
        if (it == 0) {
            r4.x = r4.y = r4.z = r4.w = 0x2C002C00u;      // (0.0625, 0.0625) fp16
        } else {
            r4 = route_l[rp * 16 + rco];
        }
        float pr[8];
#pragma unroll
        for (int a8 = 0; a8 < 8; ++a8) {
            const int ao = aoh * 8 + a8;
            float v = (a8 < 4) ? ((a8 == 0) ? bia0.x : (a8 == 1) ? bia0.y : (a8 == 2) ? bia0.z : bia0.w)
                               : ((a8 == 4) ? bia1.x : (a8 == 5) ? bia1.y : (a8 == 6) ? bia1.z : bia1.w);
            v = fdot2u(vl[VIDX(rp, 0, ao, rco)], r4.x, v);
            v = fdot2u(vl[VIDX(rp, 1, ao, rco)], r4.y, v);
            v = fdot2u(vl[VIDX(rp, 2, ao, rco)], r4.z, v);
            v = fdot2u(vl[VIDX(rp, 3, ao, rco)], r4.w, v);
            pr[a8] = v;
        }
        float sq = 0.f;
#pragma unroll
        for (int a8 = 0; a8 < 8; ++a8) sq += pr[a8] * pr[a8];
        sq += __shfl_xor(sq, 1);                           // partner ao-half
        const float scale = __builtin_amdgcn_sqrtf(sq) * __builtin_amdgcn_rcpf(1.f + sq);
        float actv[8];
#pragma unroll
        for (int a8 = 0; a8 < 8; ++a8) actv[a8] = pr[a8] * scale;

        if (it < 2) {
            // agreement: in-lane partials over own 8 ao, per ci; combine halves
            float part[8];
#pragma unroll
            for (int cp = 0; cp < 4; ++cp) {
                float e = 0.f, o = 0.f;
#pragma unroll
                for (int a8 = 0; a8 < 8; ++a8) {
                    const float2 f = up16(vl[VIDX(rp, cp, aoh * 8 + a8, rco)]);
                    e += f.x * actv[a8];
                    o += f.y * actv[a8];
                }
                part[cp * 2] = e; part[cp * 2 + 1] = o;
            }
#pragma unroll
            for (int ci = 0; ci < 8; ++ci) part[ci] += __shfl_xor(part[ci], 1);
            if (aoh == 0) {
#pragma unroll
                for (int ci = 0; ci < 8; ++ci) {
                    float* lp = &logit_l[(rp * 8 + ci) * 16 + rco];
                    if (it == 0) *lp = part[ci];
                    else         *lp += part[ci];
                }
            }
            __syncthreads();
        } else {
            // final: direct coalesced reg->global store
            const size_t base = ((size_t)((b * 32 + h) * 32 + w0)) * 256;
            float* dst = out + base + rp * 256 + rco * 16 + aoh * 8;
            *(float4*)dst       = make_float4(actv[0], actv[1], actv[2], actv[3]);
            *(float4*)(dst + 4) = make_float4(actv[4], actv[5], actv[6], actv[7]);
        }
    }
}

extern "C" void kernel_launch(void* const* d_in, const int* in_sizes, int n_in,
                              void* d_out, int out_size, void* d_ws, size_t ws_size,
                              hipStream_t stream) {
    const float* x  = (const float*)d_in[0];
    const float* W  = (const float*)d_in[1];
    const float* bb = (const float*)d_in[2];
    float* out = (float*)d_out;
    f16* xb = (f16*)((char*)d_ws + XB_OFF);
    f16* Wt = (f16*)((char*)d_ws + WT_OFF);

    hipLaunchKernelGGL(prep, dim3(4608 + 25), dim3(256), 0, stream, x, W, xb, Wt);
    hipLaunchKernelGGL(caps_v8, dim3(2048), dim3(256), 0, stream, xb, Wt, bb, out);
}

// Round 10
// 145.499 us; speedup vs baseline: 1.1580x; 1.1580x over previous
//
#include <hip/hip_runtime.h>
#include <hip/hip_fp16.h>
#include <math.h>

// ConvCapsuleLayer v9: v7 structure (3 blocks/CU) + register-cached routing votes.
//   conv:    MFMA fp16, depth-1 A-prefetch + depth-2 B-prefetch (v7).
//   routing: votes stored per-routing-thread contiguous (vl[tid*36+...]),
//            loaded ONCE as 8x ds_read_b128 into registers; all 3 iterations
//            pure VALU. Direct coalesced reg->global output.
// x: [16,32,32,8,32] f32; W: [5,5,32,256] f32; b: [1,1,16,16] f32
// out: [16,32,32,16,16] f32

typedef _Float16 f16;
typedef __attribute__((ext_vector_type(2))) _Float16 f16x2;
typedef __attribute__((ext_vector_type(8))) _Float16 f16x8;
typedef __attribute__((ext_vector_type(4))) float f32x4;

#define STRIDE_CI 1944   // hw per ci slice: 5*12*32=1920 (+24)
#define XB_OFF 0
#define WT_OFF 9437184   // bytes: 16*32*36*256*2

static __device__ __forceinline__ float2 up16(unsigned int u) {
    union { unsigned int u; f16 h[2]; } c; c.u = u;
    return make_float2((float)c.h[0], (float)c.h[1]);
}

static __device__ __forceinline__ float fdot2u(unsigned int a, unsigned int b, float c) {
#if __has_builtin(__builtin_amdgcn_fdot2)
    union { unsigned int u; f16x2 h; } ua, ub;
    ua.u = a; ub.u = b;
    return __builtin_amdgcn_fdot2(ua.h, ub.h, c, false);
#else
    const float2 fa = up16(a), fb = up16(b);
    return c + fa.x * fb.x + fa.y * fb.y;
#endif
}

__global__ void prep(const float* __restrict__ x, const float* __restrict__ W,
                     f16* __restrict__ xb, f16* __restrict__ Wt) {
    __shared__ f16 lw[32 * 260];
    const int tid = threadIdx.x;
    const int bid = blockIdx.x;
    if (bid < 4608) {
        const int e4 = (bid * 256 + tid) * 4;
        const int c = e4 & 255;
        const int pix = e4 >> 8;
        const int wp = pix % 36;
        const int t = pix / 36;
        const int h = t & 31;
        const int b = t >> 5;
        const int w = wp - 2;
        f16 o[4] = {(f16)0.f, (f16)0.f, (f16)0.f, (f16)0.f};
        if ((unsigned)w < 32u) {
            const float4 v = *(const float4*)&x[(((b * 32 + h) * 32 + w) * 256) + c];
            o[0] = (f16)v.x; o[1] = (f16)v.y; o[2] = (f16)v.z; o[3] = (f16)v.w;
        }
        *(unsigned long long*)&xb[e4] = *(unsigned long long*)o;
    } else {
        const int k5 = bid - 4608;
        for (int rep = 0; rep < 32; ++rep) {
            const int idx = rep * 256 + tid;
            const int ai = idx >> 8, cc = idx & 255;
            lw[ai * 260 + cc] = (f16)W[(k5 * 32 + ai) * 256 + cc];
        }
        __syncthreads();
        for (int rep = 0; rep < 32; ++rep) {
            const int o = rep * 256 + tid;
            const int cc = o >> 5, ai = o & 31;
            Wt[k5 * 8192 + o] = lw[ai * 260 + cc];
        }
    }
}

// ---------------- fused conv + routing ----------------
__global__ __launch_bounds__(256, 3)
void caps_v9(const f16* __restrict__ xb, const f16* __restrict__ Wt,
             const float* __restrict__ bptr, float* __restrict__ out) {
    // conv phase: patch fp16[8*1944] = 31104 B
    // route phase: vl u32 [thread 256][36] = 36864 B (row = routing thread,
    //              slot = cp*8 + (ao&7); stride 36 => b128 reads conflict-free)
    __shared__ __align__(16) unsigned char smraw[36864];
    f16* patch = (f16*)smraw;
    unsigned int* vl = (unsigned int*)smraw;
    __shared__ __align__(16) uint4 route_l[8 * 16];   // fp16 ci-pair quads per (p,co)
    __shared__ float logit_l[8 * 8 * 17];             // [p][ci][co pad17]

    const int tid = threadIdx.x;
    const int lane = tid & 63;
    const int wv = tid >> 6;
    const int bid = blockIdx.x;
    const int w0 = (bid & 3) * 8;
    const int h = (bid >> 2) & 31;
    const int b = bid >> 7;

    // routing thread mapping + bias in registers
    const int rp  = tid >> 5;
    const int rco = (tid >> 1) & 15;
    const int aoh = tid & 1;
    float bia[8];
    {
        const float4 b0 = *(const float4*)&bptr[rco * 16 + aoh * 8];
        const float4 b1 = *(const float4*)&bptr[rco * 16 + aoh * 8 + 4];
        bia[0] = b0.x; bia[1] = b0.y; bia[2] = b0.z; bia[3] = b0.w;
        bia[4] = b1.x; bia[5] = b1.y; bia[6] = b1.z; bia[7] = b1.w;
    }

    // ---- stage input patch ----
    for (int e = tid; e < 1920; e += 256) {
        const int pos = e >> 5;
        const int ci = (e >> 2) & 7;
        const int s = e & 3;
        const int dh = pos / 12, dw = pos - dh * 12;
        const int gh = h + dh - 2;
        f16x8 v = {};
        if ((unsigned)gh < 32u)
            v = *(const f16x8*)&xb[(((b * 32 + gh) * 36) + (w0 + dw)) * 256 + ci * 32 + s * 8];
        *(f16x8*)&patch[ci * STRIDE_CI + pos * 32 + s * 8] = v;
    }
    __syncthreads();

    // ---- conv: M=64 (p*8+ci), N=256 (co*16+ao), K=800 ----
    const int g = lane >> 4;
    const int q = lane & 15;
    const f16* aptr = patch + (lane & 7) * STRIDE_CI + ((lane >> 3) & 1) * 32 + g * 8;
    const f16* bbase = Wt + (wv * 64 + q) * 32 + g * 8;

    f32x4 acc[4][4];
#pragma unroll
    for (int rb = 0; rb < 4; ++rb)
#pragma unroll
        for (int ct = 0; ct < 4; ++ct) acc[rb][ct] = (f32x4)0.f;

    f16x8 Bc[4], Bn[4];
    f16x8 Ac[4], An[4];
#pragma unroll
    for (int ct = 0; ct < 4; ++ct) {
        Bc[ct] = *(const f16x8*)(bbase + ct * 512);            // k5 = 0
        Bn[ct] = *(const f16x8*)(bbase + 8192 + ct * 512);     // k5 = 1
    }
#pragma unroll
    for (int rb = 0; rb < 4; ++rb)
        Ac[rb] = *(const f16x8*)(aptr + rb * 64);              // k5 = 0

    int k5 = 0;
#pragma unroll
    for (int kh = 0; kh < 5; ++kh) {
#pragma unroll
        for (int kw = 0; kw < 5; ++kw) {
            if (k5 < 24) {                                     // prefetch A for k5+1
                const int n = k5 + 1;
                const f16* apn = aptr + ((n / 5) * 12 + (n % 5)) * 32;
#pragma unroll
                for (int rb = 0; rb < 4; ++rb)
                    An[rb] = *(const f16x8*)(apn + rb * 64);
            }
            f16x8 Bf[4];
            if (k5 < 23) {                                     // prefetch B for k5+2
                const f16* bf = bbase + (k5 + 2) * 8192;
#pragma unroll
                for (int ct = 0; ct < 4; ++ct)
                    Bf[ct] = *(const f16x8*)(bf + ct * 512);
            }
#pragma unroll
            for (int rb = 0; rb < 4; ++rb)
#pragma unroll
                for (int ct = 0; ct < 4; ++ct)
                    acc[rb][ct] = __builtin_amdgcn_mfma_f32_16x16x32_f16(
                        Ac[rb], Bc[ct], acc[rb][ct], 0, 0, 0);
#pragma unroll
            for (int rb = 0; rb < 4; ++rb) Ac[rb] = An[rb];
#pragma unroll
            for (int ct = 0; ct < 4; ++ct) { Bc[ct] = Bn[ct]; Bn[ct] = Bf[ct]; }
            ++k5;
        }
    }
    // acc[rb][ct][j] = votes[p=rb*2+(g>>1)][ci=(g&1)*4+j][co=wv*4+ct][ao=q]
    __syncthreads();   // patch dead — safe to overwrite with vl

    // ---- votes -> LDS rows: vl[row*36 + cp*8 + (ao&7)], row = p*32+co*2+(ao>>3) ----
#pragma unroll
    for (int rb = 0; rb < 4; ++rb) {
        const int p = rb * 2 + (g >> 1);
        const int cpb = (g & 1) * 2;
        const int rowp = p * 32 + (q >> 3);
#pragma unroll
        for (int ct = 0; ct < 4; ++ct) {
            const int co = wv * 4 + ct;
            union { f16 h[2]; unsigned int u; } c0, c1;
            c0.h[0] = (f16)acc[rb][ct].x; c0.h[1] = (f16)acc[rb][ct].y;
            c1.h[0] = (f16)acc[rb][ct].z; c1.h[1] = (f16)acc[rb][ct].w;
            const int base = (rowp + co * 2) * 36 + cpb * 8 + (q & 7);
            vl[base] = c0.u;
            vl[base + 8] = c1.u;
        }
    }
    __syncthreads();

    // ---- load own 32 votes into registers (8x ds_read_b128, conflict-free) ----
    unsigned int varr[32];
#pragma unroll
    for (int cp = 0; cp < 4; ++cp) {
        const uint4 a = *(const uint4*)&vl[tid * 36 + cp * 8];
        const uint4 c = *(const uint4*)&vl[tid * 36 + cp * 8 + 4];
        varr[cp * 8 + 0] = a.x; varr[cp * 8 + 1] = a.y;
        varr[cp * 8 + 2] = a.z; varr[cp * 8 + 3] = a.w;
        varr[cp * 8 + 4] = c.x; varr[cp * 8 + 5] = c.y;
        varr[cp * 8 + 6] = c.z; varr[cp * 8 + 7] = c.w;
    }

    // ---- routing core: thread = (rp, rco, aoh); votes in varr ----
    unsigned int* route_d = (unsigned int*)route_l;
    float actv[8];

    for (int it = 0; it < 3; ++it) {
        if (it > 0) {
            // softmax over co; pack route as fp16 ci-pairs into route_l[p*16+co]
            for (int i = tid; i < 1024; i += 256) {
                const int pp = i >> 7, ci = (i >> 4) & 7, co = i & 15;
                float lg = logit_l[(pp * 8 + ci) * 17 + co];
                float mx = lg;
#pragma unroll
                for (int m = 1; m < 16; m <<= 1) mx = fmaxf(mx, __shfl_xor(mx, m));
                float e = __expf(lg - mx);
                float s = e;
#pragma unroll
                for (int m = 1; m < 16; m <<= 1) s += __shfl_xor(s, m);
                const float r = e * __builtin_amdgcn_rcpf(s);
                const float rother = __shfl_xor(r, 16);   // partner ci^1
                if (((tid >> 4) & 1) == 0) {              // even-ci lanes pack
                    union { f16 h[2]; unsigned int u; } pk;
                    pk.h[0] = (f16)r; pk.h[1] = (f16)rother;
                    route_d[(pp * 16 + co) * 4 + (ci >> 1)] = pk.u;
                }
            }
            __syncthreads();
        }

        // preact + squash: pure VALU on varr
        uint4 r4;
        if (it == 0) {
            r4.x = r4.y = r4.z = r4.w = 0x2C002C00u;      // (0.0625, 0.0625) fp16
        } else {
            r4 = route_l[rp * 16 + rco];
        }
        float pr[8];
#pragma unroll
        for (int a8 = 0; a8 < 8; ++a8) {
            float v = bia[a8];
            v = fdot2u(varr[a8],      r4.x, v);
            v = fdot2u(varr[8 + a8],  r4.y, v);
            v = fdot2u(varr[16 + a8], r4.z, v);
            v = fdot2u(varr[24 + a8], r4.w, v);
            pr[a8] = v;
        }
        float sq = 0.f;
#pragma unroll
        for (int a8 = 0; a8 < 8; ++a8) sq += pr[a8] * pr[a8];
        sq += __shfl_xor(sq, 1);                           // partner ao-half
        const float scale = __builtin_amdgcn_sqrtf(sq) * __builtin_amdgcn_rcpf(1.f + sq);
#pragma unroll
        for (int a8 = 0; a8 < 8; ++a8) actv[a8] = pr[a8] * scale;

        if (it < 2) {
            // agreement: pure VALU on varr; combine ao-halves via 1 shfl per ci
            float part[8];
#pragma unroll
            for (int cp = 0; cp < 4; ++cp) {
                float e = 0.f, o = 0.f;
#pragma unroll
                for (int a8 = 0; a8 < 8; ++a8) {
                    const float2 f = up16(varr[cp * 8 + a8]);
                    e += f.x * actv[a8];
                    o += f.y * actv[a8];
                }
                part[cp * 2] = e; part[cp * 2 + 1] = o;
            }
#pragma unroll
            for (int ci = 0; ci < 8; ++ci) part[ci] += __shfl_xor(part[ci], 1);
            if (aoh == 0) {
#pragma unroll
                for (int ci = 0; ci < 8; ++ci) {
                    float* lp = &logit_l[(rp * 8 + ci) * 17 + rco];
                    if (it == 0) *lp = part[ci];
                    else         *lp += part[ci];
                }
            }
            __syncthreads();
        } else {
            // final: direct coalesced reg->global store
            const size_t base = ((size_t)((b * 32 + h) * 32 + w0)) * 256;
            float* dst = out + base + rp * 256 + rco * 16 + aoh * 8;
            *(float4*)dst       = make_float4(actv[0], actv[1], actv[2], actv[3]);
            *(float4*)(dst + 4) = make_float4(actv[4], actv[5], actv[6], actv[7]);
        }
    }
}

extern "C" void kernel_launch(void* const* d_in, const int* in_sizes, int n_in,
                              void* d_out, int out_size, void* d_ws, size_t ws_size,
                              hipStream_t stream) {
    const float* x  = (const float*)d_in[0];
    const float* W  = (const float*)d_in[1];
    const float* bb = (const float*)d_in[2];
    float* out = (float*)d_out;
    f16* xb = (f16*)((char*)d_ws + XB_OFF);
    f16* Wt = (f16*)((char*)d_ws + WT_OFF);

    hipLaunchKernelGGL(prep, dim3(4608 + 25), dim3(256), 0, stream, x, W, xb, Wt);
    hipLaunchKernelGGL(caps_v9, dim3(2048), dim3(256), 0, stream, xb, Wt, bb, out);
}